// Round 15
// baseline (309.456 us; speedup 1.0000x reference)
//
#include <hip/hip_runtime.h>

#define NB 1024
#define NT 256
#define IND 10
#define HID 64

#define KSTEPS 14              // K = 448 (14 x 32)
#define XS 456                 // X row stride in halves (456/8=57 odd -> conflict-free b128)
#define WMF_HALVES (KSTEPS * 4 * 64 * 8)   // 28672 halves = 57344 B

typedef short bf16x8 __attribute__((ext_vector_type(8)));
typedef float f32x4 __attribute__((ext_vector_type(4)));
typedef unsigned u32x4 __attribute__((ext_vector_type(4)));

__device__ __forceinline__ int qmap(int kk) {
    if (kk < 10) return 1 + kk;
    if (kk < 20) return 11 * (kk - 10 + 1);
    int i = (kk - 20) / 10, c = (kk - 20) % 10;
    return 11 * (i + 1) + 1 + c;
}

__device__ __forceinline__ unsigned bf16rne(float x) {
    unsigned u = __float_as_uint(x);
    return (u + 0x7fffu + ((u >> 16) & 1u)) >> 16;
}
__device__ __forceinline__ unsigned pk2(float a, float b) {
    return bf16rne(a) | (bf16rne(b) << 16);
}
// fast pack: round-half-up then byte-perm the two high halves into one dword
__device__ __forceinline__ unsigned pk2f(float a, float b) {
    unsigned ua = __float_as_uint(a) + 0x8000u;
    unsigned ub = __float_as_uint(b) + 0x8000u;
    return __builtin_amdgcn_perm(ub, ua, 0x07060302u);
}

// X column semantics (K=448):
//  [0,128):   P (wave slice w at 32w+i, i<30; scaled by inv_k for comps<20)
//  [128,256): rel0 * P
//  [256,384): rel1 * P
//  [384,400): rel2 * Pd (Pd = P[0..9], P[10], P[20..24])
//  [400,410): rel ; [410,420): F ; [420,424): ttv, ttv*rel0, ttv*rel1, ttv*rel2
//  [424]: gate ; [425]: 1.0 (bias) ; rest 0
__device__ float wm_value(int kk, int j, const float* __restrict__ W1,
                          const float* __restrict__ b1) {
    if (kk < 384) {
        int sec = kk >> 7;
        int rem = kk & 127;
        int w = rem >> 5, i = rem & 31;
        if (i >= 30) return 0.f;
        int q = qmap(30 * w + i);
        if (sec == 0) return W1[(11 + q) * 64 + j] + W1[(132 + q) * 64 + j];
        if (sec == 1) return W1[(253 + q) * 64 + j];
        return W1[(374 + q) * 64 + j];
    }
    if (kk < 400) {
        int i = kk - 384;
        if (i < 10) return W1[(496 + i) * 64 + j];
        if (i == 10) return W1[506 * 64 + j];
        return W1[(507 + (i - 11)) * 64 + j];
    }
    if (kk < 410) return W1[(1 + (kk - 400)) * 64 + j];
    if (kk < 420) return W1[(512 + (kk - 410)) * 64 + j];
    if (kk == 420) return W1[11 * 64 + j] + W1[132 * 64 + j];
    if (kk == 421) return W1[253 * 64 + j];
    if (kk == 422) return W1[374 * 64 + j];
    if (kk == 423) return W1[495 * 64 + j];
    if (kk == 424) return W1[0 * 64 + j];
    if (kk == 425) return b1[j];
    return 0.f;
}

// Wmf in exact B-fragment order: record (s, jb) is 64 lanes x 8 halves:
// lane (n = lane&15, quad = lane>>4) holds Wm[32s + quad*8 + idx][16jb + n].
__global__ void pack_mfma_kernel(const float* __restrict__ W1,
                                 const float* __restrict__ b1,
                                 unsigned short* __restrict__ Wmf) {
    int idx = blockIdx.x * 256 + threadIdx.x;
    if (idx >= WMF_HALVES) return;
    int half = idx & 7;
    int lane = (idx >> 3) & 63;
    int rec = idx >> 9;           // s*4 + jb
    int s = rec >> 2, jb = rec & 3;
    int kk = 32 * s + (lane >> 4) * 8 + half;
    int j = 16 * jb + (lane & 15);
    Wmf[idx] = (unsigned short)bf16rne(wm_value(kk, j, W1, b1));
}

// ---------------------------------------------------------------------------
// presig v9 (unchanged from r14: 116 us, MFMA j-phase, absmax 1.0).
// ---------------------------------------------------------------------------
__global__ __launch_bounds__(256, 1) void presig9_kernel(
    const float* __restrict__ features, const unsigned short* __restrict__ Wmf,
    float* __restrict__ pre1) {
    const int b = blockIdx.x;
    const int tid = threadIdx.x;
    const int l = tid & 63;
    const int wu = tid >> 6;

    __shared__ __align__(16) float sF[NT * IND];
    __shared__ __align__(16) unsigned short sX[64 * XS];
    __shared__ float sBase[128];

    {
        const float4* src = (const float4*)(features + b * (NT * IND));
        float4* dst = (float4*)sF;
        for (int e = tid; e < NT * IND / 4; e += 256) dst[e] = src[e];
    }
    float f0[IND];
#pragma unroll
    for (int c = 0; c < IND; ++c) f0[c] = features[b * (NT * IND) + c];

    if (tid < 128) sBase[tid] = 0.f;
    __syncthreads();   // B0

    for (int tile = 0; tile < 4; ++tile) {
        const int t0 = tile * 64;

        const int r = t0 + l;
        float rf = (float)r;
        float fr[IND], rel[IND], inc[IND];
#pragma unroll
        for (int c = 0; c < IND; ++c) fr[c] = sF[r * IND + c];
#pragma unroll
        for (int c = 0; c < IND; ++c) rel[c] = fr[c] - f0[c];
        {
            bool last = (r >= NT - 1);
#pragma unroll
            for (int c = 0; c < IND; ++c)
                inc[c] = last ? 0.f : (sF[(r + 1) * IND + c] - fr[c]);
        }
        float p[30], own[30];
        if (wu == 0) {
#pragma unroll
            for (int c = 0; c < 10; ++c) p[c] = rf * inc[c];
#pragma unroll
            for (int i = 0; i < 10; ++i) p[10 + i] = rel[i];
#pragma unroll
            for (int c = 0; c < 10; ++c) p[20 + c] = rel[0] * inc[c];
        } else {
            const int i0 = 3 * wu - 2;
#pragma unroll
            for (int q = 0; q < 30; ++q) {
                int i = i0 + q / 10, c = q % 10;
                p[q] = rel[i] * inc[c];
            }
        }
#pragma unroll
        for (int i = 0; i < 30; ++i) own[i] = p[i];
#pragma unroll
        for (int dsh = 0; dsh < 6; ++dsh) {
            const int d = 1 << dsh;
            bool ok = (l >= d);
#pragma unroll
            for (int i = 0; i < 30; ++i) {
                float v = __shfl_up(p[i], d, 64);
                if (ok) p[i] += v;
            }
        }
        float inv_r = (r > 0) ? 1.f / rf : 0.f;
        float v[30];
#pragma unroll
        for (int i = 0; i < 30; ++i) {
            float x = sBase[wu * 32 + i] + p[i] - own[i];
            if (wu == 0 && i < 20) x *= inv_r;
            v[i] = x;
        }

        {
            float g0 = rel[0], g1 = rel[1];
            uint4* xr = (uint4*)&sX[l * XS];
            uint4* x0 = (uint4*)&sX[l * XS + 128];
            uint4* x1 = (uint4*)&sX[l * XS + 256];
#pragma unroll
            for (int q = 0; q < 3; ++q) {
                uint4 tr, t0v, t1v;
                tr.x = pk2(v[8*q+0], v[8*q+1]); tr.y = pk2(v[8*q+2], v[8*q+3]);
                tr.z = pk2(v[8*q+4], v[8*q+5]); tr.w = pk2(v[8*q+6], v[8*q+7]);
                t0v.x = pk2(g0*v[8*q+0], g0*v[8*q+1]); t0v.y = pk2(g0*v[8*q+2], g0*v[8*q+3]);
                t0v.z = pk2(g0*v[8*q+4], g0*v[8*q+5]); t0v.w = pk2(g0*v[8*q+6], g0*v[8*q+7]);
                t1v.x = pk2(g1*v[8*q+0], g1*v[8*q+1]); t1v.y = pk2(g1*v[8*q+2], g1*v[8*q+3]);
                t1v.z = pk2(g1*v[8*q+4], g1*v[8*q+5]); t1v.w = pk2(g1*v[8*q+6], g1*v[8*q+7]);
                xr[wu * 4 + q] = tr; x0[wu * 4 + q] = t0v; x1[wu * 4 + q] = t1v;
            }
            {
                uint4 tr, t0v, t1v;
                tr.x = pk2(v[24], v[25]); tr.y = pk2(v[26], v[27]);
                tr.z = pk2(v[28], v[29]); tr.w = 0u;
                t0v.x = pk2(g0*v[24], g0*v[25]); t0v.y = pk2(g0*v[26], g0*v[27]);
                t0v.z = pk2(g0*v[28], g0*v[29]); t0v.w = 0u;
                t1v.x = pk2(g1*v[24], g1*v[25]); t1v.y = pk2(g1*v[26], g1*v[27]);
                t1v.z = pk2(g1*v[28], g1*v[29]); t1v.w = 0u;
                xr[wu * 4 + 3] = tr; x0[wu * 4 + 3] = t0v; x1[wu * 4 + 3] = t1v;
            }
        }
        if (wu == 0) {
            float g2 = rel[2];
            float ttv = 0.5f * (rf - 1.f) * inv_r;
            float gate = (r > 0) ? 1.f : 0.f;
            uint4* xe = (uint4*)&sX[l * XS + 384];
            uint4 u;
            u.x = pk2(g2*v[0], g2*v[1]);  u.y = pk2(g2*v[2], g2*v[3]);
            u.z = pk2(g2*v[4], g2*v[5]);  u.w = pk2(g2*v[6], g2*v[7]);
            xe[0] = u;
            u.x = pk2(g2*v[8], g2*v[9]);  u.y = pk2(g2*v[10], g2*v[20]);
            u.z = pk2(g2*v[21], g2*v[22]); u.w = pk2(g2*v[23], g2*v[24]);
            xe[1] = u;
            u.x = pk2(rel[0], rel[1]); u.y = pk2(rel[2], rel[3]);
            u.z = pk2(rel[4], rel[5]); u.w = pk2(rel[6], rel[7]);
            xe[2] = u;
            u.x = pk2(rel[8], rel[9]); u.y = pk2(fr[0], fr[1]);
            u.z = pk2(fr[2], fr[3]);   u.w = pk2(fr[4], fr[5]);
            xe[3] = u;
            u.x = pk2(fr[6], fr[7]); u.y = pk2(fr[8], fr[9]);
            u.z = pk2(ttv, ttv * rel[0]); u.w = pk2(ttv * rel[1], ttv * rel[2]);
            xe[4] = u;
            u.x = pk2(gate, 1.0f); u.y = 0u; u.z = 0u; u.w = 0u;
            xe[5] = u;
            u.x = 0u; u.y = 0u; u.z = 0u; u.w = 0u;
            xe[6] = u; xe[7] = u;
        }
        if (l == 63) {
#pragma unroll
            for (int i = 0; i < 30; ++i) sBase[wu * 32 + i] += p[i];
        }
        __syncthreads();   // Bx

        {
            const int m = l & 15, quad = l >> 4;
            const unsigned short* arow = &sX[(16 * wu + m) * XS + 8 * quad];
            const bf16x8* bp = (const bf16x8*)Wmf;
            f32x4 ac0 = {0.f, 0.f, 0.f, 0.f}, ac1 = ac0, ac2 = ac0, ac3 = ac0;
#pragma unroll
            for (int s = 0; s < KSTEPS; ++s) {
                bf16x8 af = *(const bf16x8*)(arow + 32 * s);
                bf16x8 bf0 = bp[(s * 4 + 0) * 64 + l];
                bf16x8 bf1 = bp[(s * 4 + 1) * 64 + l];
                bf16x8 bf2 = bp[(s * 4 + 2) * 64 + l];
                bf16x8 bf3 = bp[(s * 4 + 3) * 64 + l];
                ac0 = __builtin_amdgcn_mfma_f32_16x16x32_bf16(af, bf0, ac0, 0, 0, 0);
                ac1 = __builtin_amdgcn_mfma_f32_16x16x32_bf16(af, bf1, ac1, 0, 0, 0);
                ac2 = __builtin_amdgcn_mfma_f32_16x16x32_bf16(af, bf2, ac2, 0, 0, 0);
                ac3 = __builtin_amdgcn_mfma_f32_16x16x32_bf16(af, bf3, ac3, 0, 0, 0);
            }
            float* op = pre1 + b * (NT * HID) + (t0 + 16 * wu) * HID + m;
            const int rowb = quad * 4;
#pragma unroll
            for (int reg = 0; reg < 4; ++reg) {
                op[(rowb + reg) * HID + 0]  = ac0[reg];
                op[(rowb + reg) * HID + 16] = ac1[reg];
                op[(rowb + reg) * HID + 32] = ac2[reg];
                op[(rowb + reg) * HID + 48] = ac3[reg];
            }
        }
        __syncthreads();   // Be
    }
}

// ---------------------------------------------------------------------------
// scan v5: MFMA-batched scan.  One wave handles 16 batches; per step the
// 64x64 GEMV is a 16x64x64 GEMM: A[m=batch][k=i]=h1 built in REGISTERS
// (prefetched pre1 + per-lane delta -> no LDS round-trip on the serial
// chain), B = W2 in 8 resident bf16 fragments, 8 chained mfma (depth 2).
// j-reduction: in-lane over 4 n-blocks + 4-stage DPP row_ror (total lands
// in ALL lanes); delta redistributed via 4 shfl + 3 selects.
// ---------------------------------------------------------------------------
template <int CTRL, int RMASK>
__device__ __forceinline__ float dpp_add(float x) {
    int v = __builtin_amdgcn_update_dpp(0, __float_as_int(x), CTRL, RMASK, 0xf, false);
    return x + __int_as_float(v);
}

__global__ __launch_bounds__(64, 1) void scan5_kernel(
    const float* __restrict__ pre1, const float* __restrict__ W1,
    const float* __restrict__ W2, const float* __restrict__ b2,
    const float* __restrict__ W3, const float* __restrict__ b3,
    float* __restrict__ out) {
    const int l = threadIdx.x;
    const int m = l & 15;        // batch sub / A-row
    const int quad = l >> 4;     // k-slice
    const int b0 = blockIdx.x * 16;

    // w1l for this lane's two i-slices (i = quad*8+ii and 32+quad*8+ii)
    float w1a[8], w1b[8];
#pragma unroll
    for (int ii = 0; ii < 8; ++ii) {
        w1a[ii] = W1[522 * 64 + quad * 8 + ii];
        w1b[ii] = W1[522 * 64 + 32 + quad * 8 + ii];
    }
    // W2 B-fragments (bf16): wf[nb][kh], lane holds W2[kh*32+quad*8+ii][nb*16+m]
    bf16x8 wf[4][2];
#pragma unroll
    for (int nb = 0; nb < 4; ++nb)
#pragma unroll
        for (int kh = 0; kh < 2; ++kh) {
            u32x4 u;
#pragma unroll
            for (int q = 0; q < 4; ++q) {
                int k0 = kh * 32 + quad * 8 + 2 * q;
                u[q] = pk2(W2[k0 * 64 + nb * 16 + m], W2[(k0 + 1) * 64 + nb * 16 + m]);
            }
            wf[nb][kh] = __builtin_bit_cast(bf16x8, u);
        }
    float b2v[4], w3v[4];
#pragma unroll
    for (int nb = 0; nb < 4; ++nb) { b2v[nb] = b2[nb * 16 + m]; w3v[nb] = W3[nb * 16 + m]; }
    float b3v = b3[0];

    const float* base = pre1 + (size_t)(b0 + m) * (NT * HID) + quad * 8;
    float delta = 0.f;

    // prefetch ring depth 2 (addresses independent of delta)
    float4 f00 = *(const float4*)(base + 0 * HID);
    float4 f01 = *(const float4*)(base + 0 * HID + 4);
    float4 f02 = *(const float4*)(base + 0 * HID + 32);
    float4 f03 = *(const float4*)(base + 0 * HID + 36);
    float4 f10 = *(const float4*)(base + 1 * HID);
    float4 f11 = *(const float4*)(base + 1 * HID + 4);
    float4 f12 = *(const float4*)(base + 1 * HID + 32);
    float4 f13 = *(const float4*)(base + 1 * HID + 36);

    for (int t = 0; t < NT; ++t) {
        int tp = (t + 2 < NT) ? (t + 2) : (NT - 1);
        float4 g0 = *(const float4*)(base + tp * HID);
        float4 g1 = *(const float4*)(base + tp * HID + 4);
        float4 g2 = *(const float4*)(base + tp * HID + 32);
        float4 g3 = *(const float4*)(base + tp * HID + 36);

        // h1 = relu(pre + delta*w1l), bf16-packed into two A-fragments
        u32x4 ua, ub;
        {
            float h0 = fmaxf(fmaf(delta, w1a[0], f00.x), 0.f);
            float h1 = fmaxf(fmaf(delta, w1a[1], f00.y), 0.f);
            float h2 = fmaxf(fmaf(delta, w1a[2], f00.z), 0.f);
            float h3 = fmaxf(fmaf(delta, w1a[3], f00.w), 0.f);
            float h4 = fmaxf(fmaf(delta, w1a[4], f01.x), 0.f);
            float h5 = fmaxf(fmaf(delta, w1a[5], f01.y), 0.f);
            float h6 = fmaxf(fmaf(delta, w1a[6], f01.z), 0.f);
            float h7 = fmaxf(fmaf(delta, w1a[7], f01.w), 0.f);
            ua[0] = pk2f(h0, h1); ua[1] = pk2f(h2, h3);
            ua[2] = pk2f(h4, h5); ua[3] = pk2f(h6, h7);
            float k0 = fmaxf(fmaf(delta, w1b[0], f02.x), 0.f);
            float k1 = fmaxf(fmaf(delta, w1b[1], f02.y), 0.f);
            float k2 = fmaxf(fmaf(delta, w1b[2], f02.z), 0.f);
            float k3 = fmaxf(fmaf(delta, w1b[3], f02.w), 0.f);
            float k4 = fmaxf(fmaf(delta, w1b[4], f03.x), 0.f);
            float k5 = fmaxf(fmaf(delta, w1b[5], f03.y), 0.f);
            float k6 = fmaxf(fmaf(delta, w1b[6], f03.z), 0.f);
            float k7 = fmaxf(fmaf(delta, w1b[7], f03.w), 0.f);
            ub[0] = pk2f(k0, k1); ub[1] = pk2f(k2, k3);
            ub[2] = pk2f(k4, k5); ub[3] = pk2f(k6, k7);
        }
        bf16x8 af0 = __builtin_bit_cast(bf16x8, ua);
        bf16x8 af1 = __builtin_bit_cast(bf16x8, ub);

        f32x4 z = {0.f, 0.f, 0.f, 0.f};
        f32x4 ac0 = __builtin_amdgcn_mfma_f32_16x16x32_bf16(af0, wf[0][0], z, 0, 0, 0);
        f32x4 ac1 = __builtin_amdgcn_mfma_f32_16x16x32_bf16(af0, wf[1][0], z, 0, 0, 0);
        f32x4 ac2 = __builtin_amdgcn_mfma_f32_16x16x32_bf16(af0, wf[2][0], z, 0, 0, 0);
        f32x4 ac3 = __builtin_amdgcn_mfma_f32_16x16x32_bf16(af0, wf[3][0], z, 0, 0, 0);
        ac0 = __builtin_amdgcn_mfma_f32_16x16x32_bf16(af1, wf[0][1], ac0, 0, 0, 0);
        ac1 = __builtin_amdgcn_mfma_f32_16x16x32_bf16(af1, wf[1][1], ac1, 0, 0, 0);
        ac2 = __builtin_amdgcn_mfma_f32_16x16x32_bf16(af1, wf[2][1], ac2, 0, 0, 0);
        ac3 = __builtin_amdgcn_mfma_f32_16x16x32_bf16(af1, wf[3][1], ac3, 0, 0, 0);

        // h2 = relu(.+b2), qv = h2*w3, sum over nb; then 16-lane ror reduce
        float s0, s1, s2, s3;
        {
            float q00 = fmaxf(ac0[0] + b2v[0], 0.f) * w3v[0];
            float q01 = fmaxf(ac1[0] + b2v[1], 0.f) * w3v[1];
            float q02 = fmaxf(ac2[0] + b2v[2], 0.f) * w3v[2];
            float q03 = fmaxf(ac3[0] + b2v[3], 0.f) * w3v[3];
            s0 = (q00 + q01) + (q02 + q03);
            float q10 = fmaxf(ac0[1] + b2v[0], 0.f) * w3v[0];
            float q11 = fmaxf(ac1[1] + b2v[1], 0.f) * w3v[1];
            float q12 = fmaxf(ac2[1] + b2v[2], 0.f) * w3v[2];
            float q13 = fmaxf(ac3[1] + b2v[3], 0.f) * w3v[3];
            s1 = (q10 + q11) + (q12 + q13);
            float q20 = fmaxf(ac0[2] + b2v[0], 0.f) * w3v[0];
            float q21 = fmaxf(ac1[2] + b2v[1], 0.f) * w3v[1];
            float q22 = fmaxf(ac2[2] + b2v[2], 0.f) * w3v[2];
            float q23 = fmaxf(ac3[2] + b2v[3], 0.f) * w3v[3];
            s2 = (q20 + q21) + (q22 + q23);
            float q30 = fmaxf(ac0[3] + b2v[0], 0.f) * w3v[0];
            float q31 = fmaxf(ac1[3] + b2v[1], 0.f) * w3v[1];
            float q32 = fmaxf(ac2[3] + b2v[2], 0.f) * w3v[2];
            float q33 = fmaxf(ac3[3] + b2v[3], 0.f) * w3v[3];
            s3 = (q30 + q31) + (q32 + q33);
        }
        s0 = dpp_add<0x128, 0xf>(s0); s1 = dpp_add<0x128, 0xf>(s1);
        s2 = dpp_add<0x128, 0xf>(s2); s3 = dpp_add<0x128, 0xf>(s3);
        s0 = dpp_add<0x124, 0xf>(s0); s1 = dpp_add<0x124, 0xf>(s1);
        s2 = dpp_add<0x124, 0xf>(s2); s3 = dpp_add<0x124, 0xf>(s3);
        s0 = dpp_add<0x122, 0xf>(s0); s1 = dpp_add<0x122, 0xf>(s1);
        s2 = dpp_add<0x122, 0xf>(s2); s3 = dpp_add<0x122, 0xf>(s3);
        s0 = dpp_add<0x121, 0xf>(s0); s1 = dpp_add<0x121, 0xf>(s1);
        s2 = dpp_add<0x121, 0xf>(s2); s3 = dpp_add<0x121, 0xf>(s3);
        s0 += b3v; s1 += b3v; s2 += b3v; s3 += b3v;
        // lane (quad g, any n) now holds deltas for batches 4g+r in s_r

        if (m == 0) {
            out[(b0 + quad * 4 + 0) * NT + t] = s0;
            out[(b0 + quad * 4 + 1) * NT + t] = s1;
            out[(b0 + quad * 4 + 2) * NT + t] = s2;
            out[(b0 + quad * 4 + 3) * NT + t] = s3;
        }
        // redistribute: lane (m across all quads) needs delta[batch m]
        {
            int src = (m >> 2) << 4;
            float d0 = __shfl(s0, src, 64);
            float d1 = __shfl(s1, src, 64);
            float d2 = __shfl(s2, src, 64);
            float d3 = __shfl(s3, src, 64);
            float t01 = (m & 1) ? d1 : d0;
            float t23 = (m & 1) ? d3 : d2;
            delta = (m & 2) ? t23 : t01;
        }
        f00 = f10; f01 = f11; f02 = f12; f03 = f13;
        f10 = g0; f11 = g1; f12 = g2; f13 = g3;
    }
}

// ---------------------------------------------------------------------------
// Fallback (round-1 fused kernel) if workspace is too small.
// ---------------------------------------------------------------------------
__global__ __launch_bounds__(256) void logsig_hedge_fallback(
    const float* __restrict__ features, const float* __restrict__ W1,
    const float* __restrict__ b1, const float* __restrict__ W2,
    const float* __restrict__ b2, const float* __restrict__ W3,
    const float* __restrict__ b3, float* __restrict__ out) {
    const int b = blockIdx.x;
    const int tid = threadIdx.x;
    const int j = tid & 63;
    const int s = tid >> 6;

    __shared__ __align__(16) float sF[NT * IND];
    __shared__ __align__(16) float sSig[128];
    __shared__ float sA[IND], sB[IND], sC[IND * IND];
    __shared__ float sRel[IND];
    __shared__ __align__(16) float sPart[4 * 64];
    __shared__ __align__(16) float sH1[64];

    for (int idx = tid; idx < NT * IND; idx += 256)
        sF[idx] = features[b * (NT * IND) + idx];
    if (tid < 100) sC[tid] = 0.f;
    else if (tid < 110) sA[tid - 100] = 0.f;
    else if (tid < 120) sB[tid - 110] = 0.f;
    else if (tid >= 121 && tid < 128) sSig[tid] = 0.f;

    float vs[32], vb[32], vc[32];
#pragma unroll
    for (int mm = 0; mm < 32; ++mm) {
        int mp = 32 * s + mm;
        if (mp < 121) {
            vs[mm] = W1[(11 + mp) * 64 + j] + W1[(132 + mp) * 64 + j];
            vb[mm] = W1[(253 + mp) * 64 + j];
            vc[mm] = W1[(374 + mp) * 64 + j];
        } else { vs[mm] = 0.f; vb[mm] = 0.f; vc[mm] = 0.f; }
    }
    float ex[17];
#pragma unroll
    for (int q = 0; q < 17; ++q) ex[q] = 0.f;
    if (s == 1) {
#pragma unroll
        for (int q = 0; q < 11; ++q) ex[q] = W1[q * 64 + j];
    } else if (s == 2) {
#pragma unroll
        for (int q = 0; q < 10; ++q) ex[q] = W1[(512 + q) * 64 + j];
        ex[10] = b1[j];
    } else if (s == 3) {
#pragma unroll
        for (int q = 0; q < 17; ++q) ex[q] = W1[(495 + q) * 64 + j];
    }
    float w2p[16];
#pragma unroll
    for (int ii = 0; ii < 16; ++ii) w2p[ii] = W2[(16 * s + ii) * 64 + j];

    float w1l = 0.f, b2j = 0.f, w3j = 0.f, b3v = 0.f;
    if (s == 0) { w1l = W1[522 * 64 + j]; b2j = b2[j]; w3j = W3[j]; b3v = b3[0]; }
    float delta = 0.f;

    __syncthreads();

    for (int m = 0; m < NT; ++m) {
        if (m > 0) {
            if (tid < 100) {
                int i = tid / 10, c = tid % 10;
                float rp = sF[(m - 1) * 10 + i] - sF[i];
                float ic = sF[m * 10 + c] - sF[(m - 1) * 10 + c];
                sC[tid] += rp * ic;
            } else if (tid < 110) {
                int i = tid - 100;
                sA[i] += (float)(m - 1) * (sF[m * 10 + i] - sF[(m - 1) * 10 + i]);
            } else if (tid < 120) {
                int i = tid - 110;
                sB[i] += sF[(m - 1) * 10 + i] - sF[i];
            }
            __syncthreads();
            float inv_k = 1.0f / (float)m;
            if (tid == 0) sSig[0] = 0.5f * (float)(m - 1) * inv_k;
            else if (tid < 11) sSig[tid] = inv_k * sA[tid - 1];
            else if (tid < 121) {
                int i = tid / 11 - 1, c = tid % 11;
                sSig[tid] = (c == 0) ? inv_k * sB[i] : sC[i * 10 + (c - 1)];
            } else if (tid < 131) {
                int f = tid - 121;
                sRel[f] = sF[m * 10 + f] - sF[f];
            }
            __syncthreads();
        }
        float part = 0.f;
        if (m > 0) {
            float pa = 0.f, pb = 0.f, pc = 0.f;
#pragma unroll
            for (int q = 0; q < 8; ++q) {
                float4 sv = *(const float4*)&sSig[32 * s + 4 * q];
                pa = fmaf(sv.x, vs[4 * q + 0], pa);
                pb = fmaf(sv.x, vb[4 * q + 0], pb);
                pc = fmaf(sv.x, vc[4 * q + 0], pc);
                pa = fmaf(sv.y, vs[4 * q + 1], pa);
                pb = fmaf(sv.y, vb[4 * q + 1], pb);
                pc = fmaf(sv.y, vc[4 * q + 1], pc);
                pa = fmaf(sv.z, vs[4 * q + 2], pa);
                pb = fmaf(sv.z, vb[4 * q + 2], pb);
                pc = fmaf(sv.z, vc[4 * q + 2], pc);
                pa = fmaf(sv.w, vs[4 * q + 3], pa);
                pb = fmaf(sv.w, vb[4 * q + 3], pb);
                pc = fmaf(sv.w, vc[4 * q + 3], pc);
            }
            part = pa + sRel[0] * pb + sRel[1] * pc;
            if (s == 3) {
                float pd = 0.f;
#pragma unroll
                for (int q = 0; q < 17; ++q) pd = fmaf(sSig[q], ex[q], pd);
                part = fmaf(sRel[2], pd, part);
            }
            if (s == 1) {
                part += ex[0];
#pragma unroll
                for (int i = 0; i < 10; ++i) part = fmaf(sRel[i], ex[1 + i], part);
            }
        }
        if (s == 2) {
            float pf = ex[10];
#pragma unroll
            for (int f = 0; f < 10; ++f) pf = fmaf(sF[m * 10 + f], ex[f], pf);
            part += pf;
        }
        sPart[s * 64 + j] = part;
        __syncthreads();
        if (s == 0) {
            float x = sPart[j] + sPart[64 + j] + sPart[128 + j] + sPart[192 + j];
            sH1[j] = fmaxf(fmaf(delta, w1l, x), 0.f);
        }
        __syncthreads();
        {
            float hp = 0.f;
#pragma unroll
            for (int q = 0; q < 4; ++q) {
                float4 hv = *(const float4*)&sH1[16 * s + 4 * q];
                hp = fmaf(hv.x, w2p[4 * q + 0], hp);
                hp = fmaf(hv.y, w2p[4 * q + 1], hp);
                hp = fmaf(hv.z, w2p[4 * q + 2], hp);
                hp = fmaf(hv.w, w2p[4 * q + 3], hp);
            }
            sPart[s * 64 + j] = hp;
        }
        __syncthreads();
        if (s == 0) {
            float x2 = sPart[j] + sPart[64 + j] + sPart[128 + j] + sPart[192 + j] + b2j;
            float h2 = fmaxf(x2, 0.f);
            float dv = h2 * w3j;
#pragma unroll
            for (int off = 32; off > 0; off >>= 1) dv += __shfl_xor(dv, off, 64);
            delta = dv + b3v;
            if (j == 0) out[b * NT + m] = delta;
        }
        __syncthreads();
    }
}

extern "C" void kernel_launch(void* const* d_in, const int* in_sizes, int n_in,
                              void* d_out, int out_size, void* d_ws, size_t ws_size,
                              hipStream_t stream) {
    const float* features = (const float*)d_in[0];
    const float* W1 = (const float*)d_in[1];
    const float* b1 = (const float*)d_in[2];
    const float* W2 = (const float*)d_in[3];
    const float* b2 = (const float*)d_in[4];
    const float* W3 = (const float*)d_in[5];
    const float* b3 = (const float*)d_in[6];
    float* out = (float*)d_out;

    const size_t wmf_bytes = (size_t)WMF_HALVES * 2;
    const size_t w_pad     = ((wmf_bytes + 255) / 256) * 256;
    const size_t pre_bytes = (size_t)NB * NT * HID * sizeof(float);  // 64 MiB
    if (ws_size >= w_pad + pre_bytes) {
        unsigned short* Wmf = (unsigned short*)d_ws;
        float* pre1 = (float*)((char*)d_ws + w_pad);
        pack_mfma_kernel<<<(WMF_HALVES + 255) / 256, 256, 0, stream>>>(W1, b1, Wmf);
        presig9_kernel<<<NB, 256, 0, stream>>>(features, Wmf, pre1);
        scan5_kernel<<<64, 64, 0, stream>>>(pre1, W1, W2, b2, W3, b3, out);
    } else {
        logsig_hedge_fallback<<<NB, 256, 0, stream>>>(features, W1, b1, W2, b2, W3, b3, out);
    }
}